// Round 7
// baseline (239.611 us; speedup 1.0000x reference)
//
#include <hip/hip_runtime.h>

#define NB  8
#define TOQ 2048
#define TIV 2048
#define HD  128

typedef float f32x4 __attribute__((ext_vector_type(4)));
typedef short s16x8 __attribute__((ext_vector_type(8)));
typedef unsigned short ushort8v __attribute__((ext_vector_type(8)));

__device__ __forceinline__ unsigned short f2bf(float f) {   // RNE f32->bf16
    unsigned u = __float_as_uint(f);
    return (unsigned short)((u + 0x7FFFu + ((u >> 16) & 1u)) >> 16);
}
__device__ __forceinline__ float bf2f(unsigned short h) {
    return __uint_as_float(((unsigned)h) << 16);
}

__device__ __forceinline__ void split8(const float4 a, const float4 b,
                                       ushort8v& h, ushort8v& l) {
    const float x[8] = {a.x, a.y, a.z, a.w, b.x, b.y, b.z, b.w};
    #pragma unroll
    for (int j = 0; j < 8; ++j) {
        const unsigned short hi = f2bf(x[j]);
        h[j] = hi;
        l[j] = f2bf(x[j] - bf2f(hi));
    }
}

// ---------------------------------------------------------------------------
// K0: VT[n][h][s] = bf16(V[n][s][h])  (4 MB scratch for PV B-fragments)
// ---------------------------------------------------------------------------
__global__ __launch_bounds__(256) void k0_vt(
    const float* __restrict__ V, unsigned short* __restrict__ VT)
{
    __shared__ unsigned short tile[64][68];
    const int n  = blockIdx.z;
    const int s0 = blockIdx.x * 64;
    const int h0 = blockIdx.y * 64;
    const int t  = threadIdx.x;

    #pragma unroll
    for (int it = 0; it < 4; ++it) {
        const int f = t + it * 256;
        const int r = f >> 4;
        const int c = f & 15;
        const float4 v = *(const float4*)&V[((size_t)(n * TIV + s0 + r)) * HD + h0 + 4 * c];
        tile[4 * c + 0][r] = f2bf(v.x);
        tile[4 * c + 1][r] = f2bf(v.y);
        tile[4 * c + 2][r] = f2bf(v.z);
        tile[4 * c + 3][r] = f2bf(v.w);
    }
    __syncthreads();

    #pragma unroll
    for (int it = 0; it < 2; ++it) {
        const int f  = t + it * 256;
        const int hh = f >> 3;
        const int sc = f & 7;
        ushort8v o;
        #pragma unroll
        for (int j = 0; j < 8; ++j) o[j] = tile[hh][8 * sc + j];
        *(ushort8v*)&VT[((size_t)(n * HD + h0 + hh)) * TIV + s0 + 8 * sc] = o;
    }
}

// ---------------------------------------------------------------------------
// K1: E = mask ? 0 : exp(Q.V^T) via split-bf16 MFMA + fused row partial sums.
// Mask tile is converted to a 2 KB LDS bitmask up-front (coalesced loads +
// __ballot) so the epilogue does ZERO scattered global loads.
// ---------------------------------------------------------------------------
__global__ __launch_bounds__(256) void k1_mfma(
    const float* __restrict__ Q, const float* __restrict__ V,
    const int* __restrict__ M, float* __restrict__ E,
    float* __restrict__ part)
{
    __shared__ unsigned short qhi[128 * 32], qlo[128 * 32];
    __shared__ unsigned short vhi[128 * 32], vlo[128 * 32];
    __shared__ unsigned int   mbits[128][4];     // [local row][32-col word]

    const int n    = blockIdx.z;
    const int tt   = blockIdx.y * 128;
    const int ts   = blockIdx.x * 128;
    const int t    = threadIdx.x;
    const int lane = t & 63;
    const int wave = t >> 6;
    const int wr   = wave >> 1;
    const int wc   = wave & 1;
    const int lr   = lane & 15;
    const int kg   = lane >> 4;

    const float* Qb = Q + ((size_t)n * TOQ + tt) * HD;
    const float* Vb = V + ((size_t)n * TIV + ts) * HD;

    // Phase 0: mask tile -> LDS bits. Wave w owns rows [32w, 32w+32).
    // Lane i reads col i (coalesced 256B/wave); ballot packs 64 cols -> 64 bits.
    const int* Mtb = M + ((size_t)n * TOQ + tt) * TIV + ts;
    #pragma unroll 8
    for (int r = 0; r < 32; ++r) {
        const int row = wave * 32 + r;
        const unsigned long long b0 = __ballot(Mtb[(size_t)row * TIV + lane] != 0);
        const unsigned long long b1 = __ballot(Mtb[(size_t)row * TIV + 64 + lane] != 0);
        if (lane == 0) {
            mbits[row][0] = (unsigned)b0;
            mbits[row][1] = (unsigned)(b0 >> 32);
            mbits[row][2] = (unsigned)b1;
            mbits[row][3] = (unsigned)(b1 >> 32);
        }
    }
    // (first __syncthreads inside the h0 loop makes mbits visible to all)

    f32x4 acc[4][4];
    #pragma unroll
    for (int i = 0; i < 4; ++i)
        #pragma unroll
        for (int j = 0; j < 4; ++j) acc[i][j] = (f32x4)0.f;

    for (int h0 = 0; h0 < HD; h0 += 32) {
        #pragma unroll
        for (int it = 0; it < 2; ++it) {
            const int i   = t + it * 256;
            const int row = i >> 2;
            const int kb  = i & 3;
            const float* qs = Qb + (size_t)row * HD + h0 + kb * 8;
            const float* vs = Vb + (size_t)row * HD + h0 + kb * 8;
            const float4 q0 = *(const float4*)qs, q1 = *(const float4*)(qs + 4);
            const float4 v0 = *(const float4*)vs, v1 = *(const float4*)(vs + 4);
            ushort8v qh, ql, vh, vl;
            split8(q0, q1, qh, ql);
            split8(v0, v1, vh, vl);
            *(ushort8v*)(qhi + i * 8) = qh;
            *(ushort8v*)(qlo + i * 8) = ql;
            *(ushort8v*)(vhi + i * 8) = vh;
            *(ushort8v*)(vlo + i * 8) = vl;
        }
        __syncthreads();

        s16x8 aH[4], aL[4];
        #pragma unroll
        for (int fm = 0; fm < 4; ++fm) {
            const int off = (wr * 64 + fm * 16 + lr) * 32 + kg * 8;
            aH[fm] = *(const s16x8*)(qhi + off);
            aL[fm] = *(const s16x8*)(qlo + off);
        }
        #pragma unroll
        for (int fn = 0; fn < 4; ++fn) {
            const int off = (wc * 64 + fn * 16 + lr) * 32 + kg * 8;
            const s16x8 bH = *(const s16x8*)(vhi + off);
            const s16x8 bL = *(const s16x8*)(vlo + off);
            #pragma unroll
            for (int fm = 0; fm < 4; ++fm) {
                acc[fm][fn] = __builtin_amdgcn_mfma_f32_16x16x32_bf16(aH[fm], bH, acc[fm][fn], 0, 0, 0);
                acc[fm][fn] = __builtin_amdgcn_mfma_f32_16x16x32_bf16(aH[fm], bL, acc[fm][fn], 0, 0, 0);
                acc[fm][fn] = __builtin_amdgcn_mfma_f32_16x16x32_bf16(aL[fm], bH, acc[fm][fn], 0, 0, 0);
            }
        }
        __syncthreads();
    }

    // epilogue: LDS mask bits + exp + coalesced E stores + row partial sums
    float rsum[4][4];
    #pragma unroll
    for (int fm = 0; fm < 4; ++fm)
        #pragma unroll
        for (int ri = 0; ri < 4; ++ri) rsum[fm][ri] = 0.f;

    #pragma unroll
    for (int fm = 0; fm < 4; ++fm) {
        #pragma unroll
        for (int ri = 0; ri < 4; ++ri) {
            const int rl  = wr * 64 + fm * 16 + kg * 4 + ri;     // local row
            const unsigned mw0 = mbits[rl][wc * 2 + 0];          // cols +0..31
            const unsigned mw1 = mbits[rl][wc * 2 + 1];          // cols +32..63
            const size_t rowbase = ((size_t)n * TOQ + tt + rl) * TIV + ts + wc * 64;
            float rs = 0.f;
            #pragma unroll
            for (int fn = 0; fn < 4; ++fn) {
                const int cb = fn * 16 + lr;                     // 0..63
                const unsigned w = (cb & 32) ? mw1 : mw0;
                const float e = ((w >> (cb & 31)) & 1u) ? 0.f : __expf(acc[fm][fn][ri]);
                E[rowbase + cb] = e;
                rs += e;
            }
            rsum[fm][ri] = rs;
        }
    }
    #pragma unroll
    for (int fm = 0; fm < 4; ++fm) {
        #pragma unroll
        for (int ri = 0; ri < 4; ++ri) {
            float s = rsum[fm][ri];
            s += __shfl_xor(s, 1, 64);
            s += __shfl_xor(s, 2, 64);
            s += __shfl_xor(s, 4, 64);
            s += __shfl_xor(s, 8, 64);
            if (lr == 0) {
                const int r = tt + wr * 64 + fm * 16 + kg * 4 + ri;
                part[((size_t)n * TOQ + r) * 32 + blockIdx.x * 2 + wc] = s;
            }
        }
    }
}

// ---------------------------------------------------------------------------
// K2: rec[row] = 1 / sum of 32 partials   (one thread per row, 2 MB total)
// ---------------------------------------------------------------------------
__global__ __launch_bounds__(256) void k2_rowsum(
    const float* __restrict__ part, float* __restrict__ rec)
{
    const int row = blockIdx.x * 256 + threadIdx.x;
    const float4* p4 = (const float4*)(part + (size_t)row * 32);
    float s = 0.f;
    #pragma unroll
    for (int i = 0; i < 8; ++i) {
        const float4 v = p4[i];
        s += (v.x + v.y) + (v.z + v.w);
    }
    rec[row] = 1.f / s;
}

// ---------------------------------------------------------------------------
// K3: barrier-free fused normalize + P-writeback + MFMA PV.
// 512 blocks x 8 waves: wave = (row-group p 0..1, k-quarter q 0..3).
// ---------------------------------------------------------------------------
__global__ __launch_bounds__(512) void k3_pv(
    float* __restrict__ EP, const unsigned short* __restrict__ VT,
    const float* __restrict__ rec, float* __restrict__ O)
{
    __shared__ float red[2][3][16][132];

    const int n    = blockIdx.y;
    const int r0   = blockIdx.x * 32;
    const int t    = threadIdx.x;
    const int wave = t >> 6;
    const int lane = t & 63;
    const int p    = wave >> 2;
    const int q    = wave & 3;
    const int lr   = lane & 15;
    const int kg   = lane >> 4;

    const int rowg = r0 + p * 16 + lr;
    const float rc = rec[n * TOQ + rowg];
    float* Erow = EP + ((size_t)n * TOQ + rowg) * TIV;
    const unsigned short* VTb = VT + (size_t)n * HD * TIV;

    f32x4 acc[8];
    #pragma unroll
    for (int fn = 0; fn < 8; ++fn) acc[fn] = (f32x4)0.f;

    const int kbase = q * 512 + kg * 8;

    #pragma unroll 2
    for (int k0 = 0; k0 < 512; k0 += 32) {
        const int k = kbase + k0;
        const float4 e0 = *(const float4*)&Erow[k];
        const float4 e1 = *(const float4*)&Erow[k + 4];
        float4 p0, p1;
        p0.x = e0.x * rc; p0.y = e0.y * rc; p0.z = e0.z * rc; p0.w = e0.w * rc;
        p1.x = e1.x * rc; p1.y = e1.y * rc; p1.z = e1.z * rc; p1.w = e1.w * rc;
        *(float4*)&Erow[k]     = p0;             // P output (f32)
        *(float4*)&Erow[k + 4] = p1;

        s16x8 a;
        a[0] = (short)f2bf(p0.x); a[1] = (short)f2bf(p0.y);
        a[2] = (short)f2bf(p0.z); a[3] = (short)f2bf(p0.w);
        a[4] = (short)f2bf(p1.x); a[5] = (short)f2bf(p1.y);
        a[6] = (short)f2bf(p1.z); a[7] = (short)f2bf(p1.w);

        #pragma unroll
        for (int fn = 0; fn < 8; ++fn) {
            const s16x8 b = *(const s16x8*)&VTb[(size_t)(fn * 16 + lr) * TIV + k];
            acc[fn] = __builtin_amdgcn_mfma_f32_16x16x32_bf16(a, b, acc[fn], 0, 0, 0);
        }
    }

    if (q != 0) {
        #pragma unroll
        for (int fn = 0; fn < 8; ++fn)
            #pragma unroll
            for (int ri = 0; ri < 4; ++ri)
                red[p][q - 1][kg * 4 + ri][fn * 16 + lr] = acc[fn][ri];
    }
    __syncthreads();
    if (q == 0) {
        #pragma unroll
        for (int fn = 0; fn < 8; ++fn) {
            #pragma unroll
            for (int ri = 0; ri < 4; ++ri) {
                const int orow = r0 + p * 16 + kg * 4 + ri;
                float o = acc[fn][ri];
                o += red[p][0][kg * 4 + ri][fn * 16 + lr];
                o += red[p][1][kg * 4 + ri][fn * 16 + lr];
                o += red[p][2][kg * 4 + ri][fn * 16 + lr];
                O[((size_t)n * TOQ + orow) * HD + fn * 16 + lr] = o;
            }
        }
    }
}

// ---------------------------------------------------------------------------
extern "C" void kernel_launch(void* const* d_in, const int* in_sizes, int n_in,
                              void* d_out, int out_size, void* d_ws, size_t ws_size,
                              hipStream_t stream)
{
    const float* Q = (const float*)d_in[0];
    const float* V = (const float*)d_in[1];
    const int*   M = (const int*)d_in[2];

    float* O = (float*)d_out;                         // [8][2048][128] f32
    float* E = O + (size_t)NB * TOQ * HD;             // [8][2048][2048] f32 (P out)

    float*          recb = (float*)d_ws;                                   // 64 KB
    float*          part = (float*)((char*)d_ws + (1 << 16));              // 2 MB
    unsigned short* VT   = (unsigned short*)((char*)d_ws + (1 << 16) + (NB * TOQ * 32 * 4)); // 4 MB

    k0_vt    <<<dim3(TIV / 64, HD / 64, NB), 256, 0, stream>>>(V, VT);
    k1_mfma  <<<dim3(TIV / 128, TOQ / 128, NB), 256, 0, stream>>>(Q, V, M, E, part);
    k2_rowsum<<<dim3(NB * TOQ / 256), 256, 0, stream>>>(part, recb);
    k3_pv    <<<dim3(TOQ / 32, NB), 512, 0, stream>>>(E, VT, recb, O);
}